// Round 12
// baseline (158.040 us; speedup 1.0000x reference)
//
#include <hip/hip_runtime.h>
#include <hip/hip_bf16.h>

// Problem constants (from reference)
#define BATCH   16384
#define C_SEL   32
#define C_TOTAL 64
#define IN_F    128
#define OUT_F   128

#define BM      64    // batch rows per job
#define NGRP    32    // mtile groups (blocks per channel)
#define NJOBS   8     // jobs per block:  NGRP*NJOBS*BM == BATCH

typedef __bf16 bf16x8 __attribute__((ext_vector_type(8)));
typedef float  f32x4  __attribute__((ext_vector_type(4)));

__device__ __forceinline__ bf16x8 cvt_bf16x8(const float4 f0, const float4 f1) {
    bf16x8 a;
    a[0] = (__bf16)f0.x; a[1] = (__bf16)f0.y; a[2] = (__bf16)f0.z; a[3] = (__bf16)f0.w;
    a[4] = (__bf16)f1.x; a[5] = (__bf16)f1.y; a[6] = (__bf16)f1.z; a[7] = (__bf16)f1.w;
    return a;
}

// 5 blocks/CU: LDS 5x32KB = 160KB exactly; VGPR cap ~102, demand ~96 (64 arch + 32 acc).
// Keeps the FULL 2-deep prefetch: in-flight = 20 waves x 512B = 10KB >= 9.2KB BW*latency.
__global__ __launch_bounds__(256, 5) void pl_mfma_kernel(
    const float* __restrict__ inp,       // (BATCH, C_SEL, IN_F)
    const float* __restrict__ weight,    // (C_TOTAL, OUT_F, IN_F)
    const float* __restrict__ bias,      // (C_TOTAL, OUT_F)
    const int*   __restrict__ channels,  // (C_SEL,)
    float*       __restrict__ out)       // (BATCH, C_SEL, OUT_F)
{
    // W[ch] as bf16 [128][128] = 32 KB; bank-conflict-free via 16B-unit XOR swizzle.
    __shared__ __bf16 ldsW[OUT_F * IN_F];

    const int bid = blockIdx.x;          // 1024 blocks
    const int c   = bid & 31;            // channel fastest
    const int g   = bid >> 5;            // mtile group 0..31
    const int ch  = channels[c];

    const int t  = threadIdx.x;
    const int w  = t >> 6;               // wave 0..3 -> rows [w*16, w*16+16) of each job
    const int l  = t & 63;
    const int lr = l & 15;               // fragment row (A) / col (B)
    const int lg = l >> 4;               // k-group 0..3
    const int rot = 2 * w;               // per-wave job rotation (de-lockstep)

    // per-lane A base (floats): job j adds j*JSTRIDE
    const size_t JSTRIDE = (size_t)NGRP * BM * C_SEL * IN_F;   // 8,388,608 floats
    const float* abase = inp + (size_t)g * BM * C_SEL * IN_F
                       + ((size_t)(w * 16 + lr) * C_SEL + (size_t)c) * IN_F + lg * 8;

    // ---- prologue: issue slot-0 and slot-1 A-loads (jobs rot, rot+1) ----
    float4 raA[8], raB[8];
    {
        const float* p0 = abase + (size_t)((0 + rot) & 7) * JSTRIDE;
        #pragma unroll
        for (int ks = 0; ks < 4; ++ks) {
            raA[2 * ks]     = *reinterpret_cast<const float4*>(p0 + ks * 32);
            raA[2 * ks + 1] = *reinterpret_cast<const float4*>(p0 + ks * 32 + 4);
        }
        const float* p1 = abase + (size_t)((1 + rot) & 7) * JSTRIDE;
        #pragma unroll
        for (int ks = 0; ks < 4; ++ks) {
            raB[2 * ks]     = *reinterpret_cast<const float4*>(p1 + ks * 32);
            raB[2 * ks + 1] = *reinterpret_cast<const float4*>(p1 + ks * 32 + 4);
        }
    }

    // ---- bias into 8 registers (lane's columns are nt*16 + lr, fixed) ----
    float bv[8];
    const float* brow = bias + (size_t)ch * OUT_F;
    #pragma unroll
    for (int nt = 0; nt < 8; ++nt) bv[nt] = brow[nt * 16 + lr];

    // ---- stage W[ch] fp32 -> bf16 into LDS once (swizzled 16B units) ----
    const float* wsrc = weight + (size_t)ch * (OUT_F * IN_F);
    #pragma unroll
    for (int i = 0; i < 8; ++i) {
        const int fidx = i * 2048 + t * 8;
        const int row  = fidx >> 7;
        const int u    = (fidx & 127) >> 3;
        const float4 f0 = *reinterpret_cast<const float4*>(wsrc + fidx);
        const float4 f1 = *reinterpret_cast<const float4*>(wsrc + fidx + 4);
        const int up = u ^ (row & 7);
        *reinterpret_cast<bf16x8*>(&ldsW[row * IN_F + up * 8]) = cvt_bf16x8(f0, f1);
    }

    __syncthreads();

    // per-lane output base (floats): job j adds j*JSTRIDE, row j2 adds j2*C_SEL*OUT_F
    float* obase = out + (size_t)g * BM * C_SEL * OUT_F
                 + ((size_t)(w * 16 + lg * 4) * C_SEL + (size_t)c) * OUT_F + lr;

    // ---- job loop over slots, 2x-unrolled; wave's job = (slot + rot) & 7 ----
    #pragma unroll
    for (int jj = 0; jj < NJOBS; jj += 2) {
        // ===== even slot jj (consumes raA) =====
        {
            const size_t jobOff = (size_t)((jj + rot) & 7) * JSTRIDE;

            bf16x8 af[4];
            #pragma unroll
            for (int ks = 0; ks < 4; ++ks) af[ks] = cvt_bf16x8(raA[2 * ks], raA[2 * ks + 1]);

            f32x4 acc[8];
            #pragma unroll
            for (int nt = 0; nt < 8; ++nt) { f32x4 z = {0.f,0.f,0.f,0.f}; acc[nt] = z; }

            #pragma unroll
            for (int ks = 0; ks < 4; ++ks) {
                #pragma unroll
                for (int nt = 0; nt < 8; ++nt) {
                    const int row = nt * 16 + lr;
                    const int u   = (ks * 4 + lg) ^ (lr & 7);
                    const bf16x8 b = *reinterpret_cast<const bf16x8*>(&ldsW[row * IN_F + u * 8]);
                    acc[nt] = __builtin_amdgcn_mfma_f32_16x16x32_bf16(af[ks], b, acc[nt], 0, 0, 0);
                }
            }

            // prefetch slot jj+2 into raA (raA fully consumed above)
            if (jj + 2 < NJOBS) {
                const float* p = abase + (size_t)((jj + 2 + rot) & 7) * JSTRIDE;
                #pragma unroll
                for (int ks = 0; ks < 4; ++ks) {
                    raA[2 * ks]     = *reinterpret_cast<const float4*>(p + ks * 32);
                    raA[2 * ks + 1] = *reinterpret_cast<const float4*>(p + ks * 32 + 4);
                }
            }

            float* o = obase + jobOff;
            #pragma unroll
            for (int j2 = 0; j2 < 4; ++j2) {
                #pragma unroll
                for (int nt = 0; nt < 8; ++nt) {
                    o[(size_t)j2 * (C_SEL * OUT_F) + nt * 16] = acc[nt][j2] + bv[nt];
                }
            }
        }
        // ===== odd slot jj+1 (consumes raB) =====
        {
            const size_t jobOff = (size_t)((jj + 1 + rot) & 7) * JSTRIDE;

            bf16x8 af[4];
            #pragma unroll
            for (int ks = 0; ks < 4; ++ks) af[ks] = cvt_bf16x8(raB[2 * ks], raB[2 * ks + 1]);

            f32x4 acc[8];
            #pragma unroll
            for (int nt = 0; nt < 8; ++nt) { f32x4 z = {0.f,0.f,0.f,0.f}; acc[nt] = z; }

            #pragma unroll
            for (int ks = 0; ks < 4; ++ks) {
                #pragma unroll
                for (int nt = 0; nt < 8; ++nt) {
                    const int row = nt * 16 + lr;
                    const int u   = (ks * 4 + lg) ^ (lr & 7);
                    const bf16x8 b = *reinterpret_cast<const bf16x8*>(&ldsW[row * IN_F + u * 8]);
                    acc[nt] = __builtin_amdgcn_mfma_f32_16x16x32_bf16(af[ks], b, acc[nt], 0, 0, 0);
                }
            }

            if (jj + 3 < NJOBS) {
                const float* p = abase + (size_t)((jj + 3 + rot) & 7) * JSTRIDE;
                #pragma unroll
                for (int ks = 0; ks < 4; ++ks) {
                    raB[2 * ks]     = *reinterpret_cast<const float4*>(p + ks * 32);
                    raB[2 * ks + 1] = *reinterpret_cast<const float4*>(p + ks * 32 + 4);
                }
            }

            float* o = obase + jobOff;
            #pragma unroll
            for (int j2 = 0; j2 < 4; ++j2) {
                #pragma unroll
                for (int nt = 0; nt < 8; ++nt) {
                    o[(size_t)j2 * (C_SEL * OUT_F) + nt * 16] = acc[nt][j2] + bv[nt];
                }
            }
        }
    }
}

extern "C" void kernel_launch(void* const* d_in, const int* in_sizes, int n_in,
                              void* d_out, int out_size, void* d_ws, size_t ws_size,
                              hipStream_t stream) {
    const float* inp      = (const float*)d_in[0];
    const float* weight   = (const float*)d_in[1];
    const float* bias     = (const float*)d_in[2];
    const int*   channels = (const int*)d_in[3];
    float*       out      = (float*)d_out;

    dim3 grid(C_SEL * NGRP);   // 1024 blocks, channel-fastest
    dim3 block(256);
    pl_mfma_kernel<<<grid, block, 0, stream>>>(inp, weight, bias, channels, out);
}

// Round 13
// 115.654 us; speedup vs baseline: 1.3665x; 1.3665x over previous
//
#include <hip/hip_runtime.h>
#include <hip/hip_bf16.h>

// Problem constants (from reference)
#define BATCH   16384
#define C_SEL   32
#define C_TOTAL 64
#define IN_F    128
#define OUT_F   128

#define BM      64    // batch rows per job
#define NGRP    32    // mtile groups (blocks per channel)
#define NJOBS   8     // jobs per block:  NGRP*NJOBS*BM == BATCH

typedef __bf16 bf16x8 __attribute__((ext_vector_type(8)));
typedef __bf16 bf16x4 __attribute__((ext_vector_type(4)));
typedef float  f32x4  __attribute__((ext_vector_type(4)));

__device__ __forceinline__ bf16x8 cvt_bf16x8(const float4 f0, const float4 f1) {
    bf16x8 a;
    a[0] = (__bf16)f0.x; a[1] = (__bf16)f0.y; a[2] = (__bf16)f0.z; a[3] = (__bf16)f0.w;
    a[4] = (__bf16)f1.x; a[5] = (__bf16)f1.y; a[6] = (__bf16)f1.z; a[7] = (__bf16)f1.w;
    return a;
}

__device__ __forceinline__ bf16x4 cvt_bf16x4(const float4 f) {
    bf16x4 a;
    a[0] = (__bf16)f.x; a[1] = (__bf16)f.y; a[2] = (__bf16)f.z; a[3] = (__bf16)f.w;
    return a;
}

// 3 blocks/CU (LDS 48KB each): dense 512B-run loads + per-wave LDS redistribute.
__global__ __launch_bounds__(256, 3) void pl_mfma_kernel(
    const float* __restrict__ inp,       // (BATCH, C_SEL, IN_F)
    const float* __restrict__ weight,    // (C_TOTAL, OUT_F, IN_F)
    const float* __restrict__ bias,      // (C_TOTAL, OUT_F)
    const int*   __restrict__ channels,  // (C_SEL,)
    float*       __restrict__ out)       // (BATCH, C_SEL, OUT_F)
{
    // W[ch] as bf16 [128][128] = 32 KB, XOR-swizzled 16B units (as before).
    __shared__ __bf16 ldsW[OUT_F * IN_F];
    // Per-wave input staging: 16 rows x 128 bf16 = 4 KB each, XOR-swizzled 16B units.
    __shared__ __bf16 ldsA[4][16 * 128];

    const int bid = blockIdx.x;          // 1024 blocks
    const int c   = bid & 31;            // channel fastest
    const int g   = bid >> 5;            // mtile group 0..31
    const int ch  = channels[c];

    const int t  = threadIdx.x;
    const int w  = t >> 6;               // wave 0..3 -> rows [w*16, w*16+16) of each job
    const int l  = t & 63;
    const int lr = l & 15;               // fragment row (A) / col (B)
    const int lg = l >> 4;               // k-group 0..3
    const int lh = l >> 5;               // dense-load: row half (0/1)
    const int lu = l & 31;               // dense-load: 16B unit within the 512B row
    const int rot = 2 * w;               // per-wave job rotation (de-lockstep)

    // dense per-lane A base: row m = g*64 + w*16 + (2i + lh), float col = lu*4.
    // load instr i: lanes 0-31 cover row 2i (512B contiguous), lanes 32-63 row 2i+1.
    const size_t JSTRIDE = (size_t)NGRP * BM * C_SEL * IN_F;   // 8,388,608 floats
    const float* aD = inp + (size_t)(g * BM + w * 16 + lh) * (C_SEL * IN_F)
                    + (size_t)c * IN_F + lu * 4;
    // instruction i adds i * 2 * C_SEL * IN_F = i * 8192 floats

    // ---- prologue: issue slot-0 and slot-1 A-loads (dense) ----
    float4 raA[8], raB[8];
    {
        const float* p0 = aD + (size_t)((0 + rot) & 7) * JSTRIDE;
        #pragma unroll
        for (int i = 0; i < 8; ++i)
            raA[i] = *reinterpret_cast<const float4*>(p0 + i * 8192);
        const float* p1 = aD + (size_t)((1 + rot) & 7) * JSTRIDE;
        #pragma unroll
        for (int i = 0; i < 8; ++i)
            raB[i] = *reinterpret_cast<const float4*>(p1 + i * 8192);
    }

    // ---- bias into 8 registers (lane's columns are nt*16 + lr, fixed) ----
    float bv[8];
    const float* brow = bias + (size_t)ch * OUT_F;
    #pragma unroll
    for (int nt = 0; nt < 8; ++nt) bv[nt] = brow[nt * 16 + lr];

    // ---- stage W[ch] fp32 -> bf16 into LDS once (swizzled 16B units) ----
    const float* wsrc = weight + (size_t)ch * (OUT_F * IN_F);
    #pragma unroll
    for (int i = 0; i < 8; ++i) {
        const int fidx = i * 2048 + t * 8;
        const int row  = fidx >> 7;
        const int u    = (fidx & 127) >> 3;
        const float4 f0 = *reinterpret_cast<const float4*>(wsrc + fidx);
        const float4 f1 = *reinterpret_cast<const float4*>(wsrc + fidx + 4);
        const int up = u ^ (row & 7);
        *reinterpret_cast<bf16x8*>(&ldsW[row * IN_F + up * 8]) = cvt_bf16x8(f0, f1);
    }

    __syncthreads();

    __bf16* sA = &ldsA[w][0];

    // per-lane output base (floats): job j adds j*JSTRIDE, row j2 adds j2*C_SEL*OUT_F
    float* obase = out + (size_t)g * BM * C_SEL * OUT_F
                 + ((size_t)(w * 16 + lg * 4) * C_SEL + (size_t)c) * OUT_F + lr;

    // ---- job loop over slots, 2x-unrolled; wave's job = (slot + rot) & 7 ----
    #pragma unroll
    for (int jj = 0; jj < NJOBS; jj += 2) {
        // ===== even slot jj (consumes raA) =====
        {
            const size_t jobOff = (size_t)((jj + rot) & 7) * JSTRIDE;

            // 1) convert landing buffer to bf16 (raA dies here)
            bf16x4 ba[8];
            #pragma unroll
            for (int i = 0; i < 8; ++i) ba[i] = cvt_bf16x4(raA[i]);

            // 2) immediately issue slot jj+2's dense loads
            if (jj + 2 < NJOBS) {
                const float* p = aD + (size_t)((jj + 2 + rot) & 7) * JSTRIDE;
                #pragma unroll
                for (int i = 0; i < 8; ++i)
                    raA[i] = *reinterpret_cast<const float4*>(p + i * 8192);
            }

            // 3) redistribute via wave-private LDS (swizzled 16B units, no barrier)
            #pragma unroll
            for (int i = 0; i < 8; ++i) {
                const int r = 2 * i + lh;
                const int e = r * 128 + (((lu >> 1) ^ (r & 7)) << 3) + ((l & 1) << 2);
                *reinterpret_cast<bf16x4*>(&sA[e]) = ba[i];
            }

            // 4) MFMA: read fragments from LDS, out[m][o] = sum_k A[m][k]*W[o][k]
            f32x4 acc[8];
            #pragma unroll
            for (int nt = 0; nt < 8; ++nt) { f32x4 z = {0.f,0.f,0.f,0.f}; acc[nt] = z; }

            #pragma unroll
            for (int ks = 0; ks < 4; ++ks) {
                const bf16x8 af = *reinterpret_cast<const bf16x8*>(
                    &sA[lr * 128 + ((((ks << 2) + lg) ^ (lr & 7)) << 3)]);
                #pragma unroll
                for (int nt = 0; nt < 8; ++nt) {
                    const int row = nt * 16 + lr;
                    const int u   = (ks * 4 + lg) ^ (lr & 7);
                    const bf16x8 b = *reinterpret_cast<const bf16x8*>(&ldsW[row * IN_F + u * 8]);
                    acc[nt] = __builtin_amdgcn_mfma_f32_16x16x32_bf16(af, b, acc[nt], 0, 0, 0);
                }
            }

            // 5) bias + store (D layout: col = lane&15, row = lg*4 + j2)
            float* o = obase + jobOff;
            #pragma unroll
            for (int j2 = 0; j2 < 4; ++j2) {
                #pragma unroll
                for (int nt = 0; nt < 8; ++nt) {
                    o[(size_t)j2 * (C_SEL * OUT_F) + nt * 16] = acc[nt][j2] + bv[nt];
                }
            }
        }
        // ===== odd slot jj+1 (consumes raB) =====
        {
            const size_t jobOff = (size_t)((jj + 1 + rot) & 7) * JSTRIDE;

            bf16x4 ba[8];
            #pragma unroll
            for (int i = 0; i < 8; ++i) ba[i] = cvt_bf16x4(raB[i]);

            if (jj + 3 < NJOBS) {
                const float* p = aD + (size_t)((jj + 3 + rot) & 7) * JSTRIDE;
                #pragma unroll
                for (int i = 0; i < 8; ++i)
                    raB[i] = *reinterpret_cast<const float4*>(p + i * 8192);
            }

            #pragma unroll
            for (int i = 0; i < 8; ++i) {
                const int r = 2 * i + lh;
                const int e = r * 128 + (((lu >> 1) ^ (r & 7)) << 3) + ((l & 1) << 2);
                *reinterpret_cast<bf16x4*>(&sA[e]) = ba[i];
            }

            f32x4 acc[8];
            #pragma unroll
            for (int nt = 0; nt < 8; ++nt) { f32x4 z = {0.f,0.f,0.f,0.f}; acc[nt] = z; }

            #pragma unroll
            for (int ks = 0; ks < 4; ++ks) {
                const bf16x8 af = *reinterpret_cast<const bf16x8*>(
                    &sA[lr * 128 + ((((ks << 2) + lg) ^ (lr & 7)) << 3)]);
                #pragma unroll
                for (int nt = 0; nt < 8; ++nt) {
                    const int row = nt * 16 + lr;
                    const int u   = (ks * 4 + lg) ^ (lr & 7);
                    const bf16x8 b = *reinterpret_cast<const bf16x8*>(&ldsW[row * IN_F + u * 8]);
                    acc[nt] = __builtin_amdgcn_mfma_f32_16x16x32_bf16(af, b, acc[nt], 0, 0, 0);
                }
            }

            float* o = obase + jobOff;
            #pragma unroll
            for (int j2 = 0; j2 < 4; ++j2) {
                #pragma unroll
                for (int nt = 0; nt < 8; ++nt) {
                    o[(size_t)j2 * (C_SEL * OUT_F) + nt * 16] = acc[nt][j2] + bv[nt];
                }
            }
        }
    }
}

extern "C" void kernel_launch(void* const* d_in, const int* in_sizes, int n_in,
                              void* d_out, int out_size, void* d_ws, size_t ws_size,
                              hipStream_t stream) {
    const float* inp      = (const float*)d_in[0];
    const float* weight   = (const float*)d_in[1];
    const float* bias     = (const float*)d_in[2];
    const int*   channels = (const int*)d_in[3];
    float*       out      = (float*)d_out;

    dim3 grid(C_SEL * NGRP);   // 1024 blocks, channel-fastest
    dim3 block(256);
    pl_mfma_kernel<<<grid, block, 0, stream>>>(inp, weight, bias, channels, out);
}

// Round 15
// 113.985 us; speedup vs baseline: 1.3865x; 1.0146x over previous
//
#include <hip/hip_runtime.h>
#include <hip/hip_bf16.h>

// Problem constants (from reference)
#define BATCH   16384
#define C_SEL   32
#define C_TOTAL 64
#define IN_F    128
#define OUT_F   128

#define BM      64    // batch rows per job
#define NGRP    32    // mtile groups (blocks per channel)
#define NJOBS   8     // jobs per block:  NGRP*NJOBS*BM == BATCH

typedef __bf16 bf16x8 __attribute__((ext_vector_type(8)));
typedef float  f32x4  __attribute__((ext_vector_type(4)));

__device__ __forceinline__ bf16x8 cvt_bf16x8(const float4 f0, const float4 f1) {
    bf16x8 a;
    a[0] = (__bf16)f0.x; a[1] = (__bf16)f0.y; a[2] = (__bf16)f0.z; a[3] = (__bf16)f0.w;
    a[4] = (__bf16)f1.x; a[5] = (__bf16)f1.y; a[6] = (__bf16)f1.z; a[7] = (__bf16)f1.w;
    return a;
}

__global__ __launch_bounds__(256, 4) void pl_mfma_kernel(
    const float* __restrict__ inp,       // (BATCH, C_SEL, IN_F)
    const float* __restrict__ weight,    // (C_TOTAL, OUT_F, IN_F)
    const float* __restrict__ bias,      // (C_TOTAL, OUT_F)
    const int*   __restrict__ channels,  // (C_SEL,)
    float*       __restrict__ out)       // (BATCH, C_SEL, OUT_F)
{
    // W[ch] as bf16 [128][128] = 32 KB; bank-conflict-free via 16B-unit XOR swizzle.
    __shared__ __bf16 ldsW[OUT_F * IN_F];

    const int bid = blockIdx.x;          // 1024 blocks
    const int c   = bid & 31;            // channel fastest
    const int g   = bid >> 5;            // mtile group 0..31
    const int ch  = channels[c];

    const int t  = threadIdx.x;
    const int w  = t >> 6;               // wave 0..3 -> rows [w*16, w*16+16) of each job
    const int l  = t & 63;
    const int lr = l & 15;               // fragment row (A) / col (B)
    const int lg = l >> 4;               // k-group 0..3
    const int rot = 2 * w;               // per-wave job rotation (de-lockstep)

    // per-lane A base (floats): job j adds j*JSTRIDE
    const size_t JSTRIDE = (size_t)NGRP * BM * C_SEL * IN_F;   // 8,388,608 floats
    const float* abase = inp + (size_t)g * BM * C_SEL * IN_F
                       + ((size_t)(w * 16 + lr) * C_SEL + (size_t)c) * IN_F + lg * 8;

    // ---- prologue: issue slot-0 and slot-1 A-loads (jobs rot, rot+1) ----
    float4 raA[8], raB[8];
    {
        const float* p0 = abase + (size_t)((0 + rot) & 7) * JSTRIDE;
        #pragma unroll
        for (int ks = 0; ks < 4; ++ks) {
            raA[2 * ks]     = *reinterpret_cast<const float4*>(p0 + ks * 32);
            raA[2 * ks + 1] = *reinterpret_cast<const float4*>(p0 + ks * 32 + 4);
        }
        const float* p1 = abase + (size_t)((1 + rot) & 7) * JSTRIDE;
        #pragma unroll
        for (int ks = 0; ks < 4; ++ks) {
            raB[2 * ks]     = *reinterpret_cast<const float4*>(p1 + ks * 32);
            raB[2 * ks + 1] = *reinterpret_cast<const float4*>(p1 + ks * 32 + 4);
        }
    }

    // ---- bias into 8 registers (lane's column is lr, fixed) ----
    float bv[8];
    const float* brow = bias + (size_t)ch * OUT_F;
    #pragma unroll
    for (int nt = 0; nt < 8; ++nt) bv[nt] = brow[nt * 16 + lr];

    // ---- stage W[ch] fp32 -> bf16 into LDS once (swizzled 16B units) ----
    const float* wsrc = weight + (size_t)ch * (OUT_F * IN_F);
    #pragma unroll
    for (int i = 0; i < 8; ++i) {
        const int fidx = i * 2048 + t * 8;
        const int row  = fidx >> 7;
        const int u    = (fidx & 127) >> 3;
        const float4 f0 = *reinterpret_cast<const float4*>(wsrc + fidx);
        const float4 f1 = *reinterpret_cast<const float4*>(wsrc + fidx + 4);
        const int up = u ^ (row & 7);
        *reinterpret_cast<bf16x8*>(&ldsW[row * IN_F + up * 8]) = cvt_bf16x8(f0, f1);
    }

    __syncthreads();

    // per-lane output base (floats): job j adds j*JSTRIDE, row j2 adds j2*C_SEL*OUT_F
    float* obase = out + (size_t)g * BM * C_SEL * OUT_F
                 + ((size_t)(w * 16 + lg * 4) * C_SEL + (size_t)c) * OUT_F + lr;

    // ---- job loop over slots, 2x-unrolled; wave's job = (slot + rot) & 7 ----
    #pragma unroll
    for (int jj = 0; jj < NJOBS; jj += 2) {
        // ===== even slot jj (consumes raA) =====
        {
            const size_t jobOff = (size_t)((jj + rot) & 7) * JSTRIDE;

            bf16x8 af[4];
            #pragma unroll
            for (int ks = 0; ks < 4; ++ks) af[ks] = cvt_bf16x8(raA[2 * ks], raA[2 * ks + 1]);

            f32x4 acc[8];
            #pragma unroll
            for (int nt = 0; nt < 8; ++nt) { f32x4 z = {0.f,0.f,0.f,0.f}; acc[nt] = z; }

            #pragma unroll
            for (int ks = 0; ks < 4; ++ks) {
                #pragma unroll
                for (int nt = 0; nt < 8; ++nt) {
                    const int row = nt * 16 + lr;
                    const int u   = (ks * 4 + lg) ^ (lr & 7);
                    const bf16x8 b = *reinterpret_cast<const bf16x8*>(&ldsW[row * IN_F + u * 8]);
                    acc[nt] = __builtin_amdgcn_mfma_f32_16x16x32_bf16(af[ks], b, acc[nt], 0, 0, 0);
                }
            }

            // prefetch slot jj+2 into raA (raA fully consumed above)
            if (jj + 2 < NJOBS) {
                const float* p = abase + (size_t)((jj + 2 + rot) & 7) * JSTRIDE;
                #pragma unroll
                for (int ks = 0; ks < 4; ++ks) {
                    raA[2 * ks]     = *reinterpret_cast<const float4*>(p + ks * 32);
                    raA[2 * ks + 1] = *reinterpret_cast<const float4*>(p + ks * 32 + 4);
                }
            }

            float* o = obase + jobOff;
            #pragma unroll
            for (int j2 = 0; j2 < 4; ++j2) {
                #pragma unroll
                for (int nt = 0; nt < 8; ++nt) {
                    o[(size_t)j2 * (C_SEL * OUT_F) + nt * 16] = acc[nt][j2] + bv[nt];
                }
            }
        }
        // ===== odd slot jj+1 (consumes raB) =====
        {
            const size_t jobOff = (size_t)((jj + 1 + rot) & 7) * JSTRIDE;

            bf16x8 af[4];
            #pragma unroll
            for (int ks = 0; ks < 4; ++ks) af[ks] = cvt_bf16x8(raB[2 * ks], raB[2 * ks + 1]);

            f32x4 acc[8];
            #pragma unroll
            for (int nt = 0; nt < 8; ++nt) { f32x4 z = {0.f,0.f,0.f,0.f}; acc[nt] = z; }

            #pragma unroll
            for (int ks = 0; ks < 4; ++ks) {
                #pragma unroll
                for (int nt = 0; nt < 8; ++nt) {
                    const int row = nt * 16 + lr;
                    const int u   = (ks * 4 + lg) ^ (lr & 7);
                    const bf16x8 b = *reinterpret_cast<const bf16x8*>(&ldsW[row * IN_F + u * 8]);
                    acc[nt] = __builtin_amdgcn_mfma_f32_16x16x32_bf16(af[ks], b, acc[nt], 0, 0, 0);
                }
            }

            if (jj + 3 < NJOBS) {
                const float* p = abase + (size_t)((jj + 3 + rot) & 7) * JSTRIDE;
                #pragma unroll
                for (int ks = 0; ks < 4; ++ks) {
                    raB[2 * ks]     = *reinterpret_cast<const float4*>(p + ks * 32);
                    raB[2 * ks + 1] = *reinterpret_cast<const float4*>(p + ks * 32 + 4);
                }
            }

            float* o = obase + jobOff;
            #pragma unroll
            for (int j2 = 0; j2 < 4; ++j2) {
                #pragma unroll
                for (int nt = 0; nt < 8; ++nt) {
                    o[(size_t)j2 * (C_SEL * OUT_F) + nt * 16] = acc[nt][j2] + bv[nt];
                }
            }
        }
    }
}

extern "C" void kernel_launch(void* const* d_in, const int* in_sizes, int n_in,
                              void* d_out, int out_size, void* d_ws, size_t ws_size,
                              hipStream_t stream) {
    const float* inp      = (const float*)d_in[0];
    const float* weight   = (const float*)d_in[1];
    const float* bias     = (const float*)d_in[2];
    const int*   channels = (const int*)d_in[3];
    float*       out      = (float*)d_out;

    dim3 grid(C_SEL * NGRP);   // 1024 blocks, channel-fastest
    dim3 block(256);
    pl_mfma_kernel<<<grid, block, 0, stream>>>(inp, weight, bias, channels, out);
}